// Round 1
// baseline (374.426 us; speedup 1.0000x reference)
//
#include <hip/hip_runtime.h>
#include <math.h>

#define BB 32
#define TT 1024
#define FF 128
#define DD 64
#define NCLS 11
constexpr float kEps = 1e-3f;
constexpr int M = BB * TT;  // 32768 rows

// ---------------------------------------------------------------- PE table
__global__ __launch_bounds__(256) void pe_kernel(float* __restrict__ pe) {
  int idx = blockIdx.x * 256 + threadIdx.x;          // 131072 total
  int t = idx >> 7, f = idx & 127;
  float div = expf(-logf(10000.0f) * (float)(f & ~1) / (float)FF);
  float ang = (float)t * div;
  pe[idx] = (f & 1) ? cosf(ang) : sinf(ang);
}

// ------------------------------------------- QKV + out2 projections (fp32)
// grid: (M/64, 4). y=0,1,2 -> q,k,v from (x+pe); y=3 -> relu(x@w1+b1)
__global__ __launch_bounds__(256) void proj_kernel(
    const float* __restrict__ x, const float* __restrict__ pe,
    const float* __restrict__ wq, const float* __restrict__ wk,
    const float* __restrict__ wv, const float* __restrict__ w1,
    const float* __restrict__ b1,
    float* __restrict__ qo, float* __restrict__ ko,
    float* __restrict__ vo, float* __restrict__ o2) {
  __shared__ float xs[64][132];       // pad 132: 2-way conflicts only
  __shared__ float wsh[64 * 64];      // half of W at a time
  const int tid = threadIdx.x;
  const int r0 = blockIdx.x * 64;
  const int y = blockIdx.y;
  const float* w = (y == 0) ? wq : (y == 1) ? wk : (y == 2) ? wv : w1;
  const bool addpe = (y < 3);

  // stage x tile (+pe)
#pragma unroll
  for (int i = 0; i < 8; ++i) {
    int idx = tid * 4 + i * 1024;     // 8192 floats
    int lr = idx >> 7, f = idx & 127;
    float4 xv = *(const float4*)&x[(size_t)(r0 + lr) * FF + f];
    if (addpe) {
      int t = (r0 + lr) & (TT - 1);
      const float4 pv = *(const float4*)&pe[t * FF + f];
      xv.x += pv.x; xv.y += pv.y; xv.z += pv.z; xv.w += pv.w;
    }
    *(float4*)&xs[lr][f] = xv;
  }

  const int tx = tid & 15, ty = tid >> 4;
  const int c0 = tx * 4, rr = ty * 4;
  float acc[4][4] = {};

  for (int half = 0; half < 2; ++half) {
    __syncthreads();                  // protect prev wsh reads (+ xs stage on first)
#pragma unroll
    for (int i = 0; i < 4; ++i) {
      int idx = tid * 4 + i * 1024;   // 4096 floats
      *(float4*)&wsh[idx] = *(const float4*)&w[half * 4096 + idx];
    }
    __syncthreads();
#pragma unroll 4
    for (int kk = 0; kk < 64; kk += 4) {
      float4 a[4], b[4];
#pragma unroll
      for (int i = 0; i < 4; ++i) a[i] = *(const float4*)&xs[rr + i][half * 64 + kk];
#pragma unroll
      for (int j = 0; j < 4; ++j) b[j] = *(const float4*)&wsh[(kk + j) * 64 + c0];
#pragma unroll
      for (int i = 0; i < 4; ++i) {
        const float av[4] = {a[i].x, a[i].y, a[i].z, a[i].w};
#pragma unroll
        for (int j = 0; j < 4; ++j) {
          acc[i][0] += av[j] * b[j].x;
          acc[i][1] += av[j] * b[j].y;
          acc[i][2] += av[j] * b[j].z;
          acc[i][3] += av[j] * b[j].w;
        }
      }
    }
  }

  float* dst = (y == 0) ? qo : (y == 1) ? ko : (y == 2) ? vo : o2;
#pragma unroll
  for (int i = 0; i < 4; ++i) {
    float4 o4 = {acc[i][0], acc[i][1], acc[i][2], acc[i][3]};
    if (y == 3) {
      const float4 bv = *(const float4*)&b1[c0];
      o4.x = fmaxf(o4.x + bv.x, 0.f);
      o4.y = fmaxf(o4.y + bv.y, 0.f);
      o4.z = fmaxf(o4.z + bv.z, 0.f);
      o4.w = fmaxf(o4.w + bv.w, 0.f);
    }
    *(float4*)&dst[(size_t)(r0 + rr + i) * DD + c0] = o4;
  }
}

// ------------------------------------------------ flash attention (fp32)
// grid: (T/256, B, S). thread -> one q row. no max-shift (scores are small),
// so K-split partials combine as simple sums.
__global__ __launch_bounds__(256) void attn_kernel(
    const float* __restrict__ qm, const float* __restrict__ km,
    const float* __restrict__ vm, float* __restrict__ po,
    float* __restrict__ pl, int ktiles) {
  __shared__ float ks[64 * 64];
  __shared__ float vs[64 * 64];
  const int b = blockIdx.y;
  const int sidx = blockIdx.z;
  const int row = blockIdx.x * 256 + threadIdx.x;    // 0..1023
  const size_t grow = (size_t)b * TT + row;

  float qreg[DD];
#pragma unroll
  for (int i = 0; i < 16; ++i) {
    const float4 t4 = *(const float4*)&qm[grow * DD + i * 4];
    qreg[i * 4 + 0] = t4.x; qreg[i * 4 + 1] = t4.y;
    qreg[i * 4 + 2] = t4.z; qreg[i * 4 + 3] = t4.w;
  }
  float o[DD] = {};
  float l = 0.f;

  const int kt0 = sidx * ktiles;
  for (int kt = kt0; kt < kt0 + ktiles; ++kt) {
    __syncthreads();                  // protect prev tile reads
    const float* kb = km + ((size_t)b * TT + kt * 64) * DD;
    const float* vb = vm + ((size_t)b * TT + kt * 64) * DD;
#pragma unroll
    for (int i = 0; i < 4; ++i) {
      int idx = threadIdx.x * 4 + i * 1024;          // 4096 floats each
      *(float4*)&ks[idx] = *(const float4*)&kb[idx];
      *(float4*)&vs[idx] = *(const float4*)&vb[idx];
    }
    __syncthreads();
    for (int j = 0; j < 64; ++j) {
      float sp0 = 0.f, sp1 = 0.f, sp2 = 0.f, sp3 = 0.f;
#pragma unroll
      for (int i = 0; i < 16; ++i) {
        const float4 kv = *(const float4*)&ks[j * 64 + i * 4];
        sp0 += qreg[i * 4 + 0] * kv.x;
        sp1 += qreg[i * 4 + 1] * kv.y;
        sp2 += qreg[i * 4 + 2] * kv.z;
        sp3 += qreg[i * 4 + 3] * kv.w;
      }
      const float p = __expf(((sp0 + sp1) + (sp2 + sp3)) * 0.125f);
      l += p;
#pragma unroll
      for (int i = 0; i < 16; ++i) {
        const float4 vv = *(const float4*)&vs[j * 64 + i * 4];
        o[i * 4 + 0] += p * vv.x;
        o[i * 4 + 1] += p * vv.y;
        o[i * 4 + 2] += p * vv.z;
        o[i * 4 + 3] += p * vv.w;
      }
    }
  }

  const size_t obase = ((size_t)sidx * M + grow) * DD;
#pragma unroll
  for (int i = 0; i < 16; ++i) {
    float4 o4 = {o[i * 4], o[i * 4 + 1], o[i * 4 + 2], o[i * 4 + 3]};
    *(float4*)&po[obase + i * 4] = o4;
  }
  pl[(size_t)sidx * M + grow] = l;
}

// ---------------------------------------------------- combine K-split parts
__global__ __launch_bounds__(256) void combine_kernel(
    const float* __restrict__ po, const float* __restrict__ pl,
    float* __restrict__ x1, int S) {
  const int idx = blockIdx.x * 256 + threadIdx.x;    // M*DD total
  const int row = idx >> 6;
  float l = 0.f;
  for (int s = 0; s < S; ++s) l += pl[(size_t)s * M + row];
  float acc = 0.f;
  for (int s = 0; s < S; ++s) acc += po[(size_t)s * M * DD + idx];
  x1[idx] = acc / l;
}

// ----------------- bn_a -> out1 -> concat -> bn1 -> logits -> softmax
// grid: M/32 blocks, 4 waves/block, wave handles 8 rows (wave-private LDS)
__global__ __launch_bounds__(256) void head_kernel(
    const float* __restrict__ x1, const float* __restrict__ o2m,
    const float* __restrict__ bn_a_gamma, const float* __restrict__ bn_a_beta,
    const float* __restrict__ bn_a_mean, const float* __restrict__ bn_a_var,
    const float* __restrict__ w0, const float* __restrict__ b0,
    const float* __restrict__ bn1_gamma, const float* __restrict__ bn1_beta,
    const float* __restrict__ bn1_mean, const float* __restrict__ bn1_var,
    const float* __restrict__ wd, const float* __restrict__ bd,
    float* __restrict__ out) {
  __shared__ float w0s[64 * 64];
  __shared__ float wds[128 * NCLS];
  __shared__ float xsh[4][64];
  __shared__ float hsh[4][128];
  __shared__ float lsh[4][16];
  const int tid = threadIdx.x;
#pragma unroll
  for (int i = 0; i < 4; ++i)
    *(float4*)&w0s[tid * 4 + i * 1024] = *(const float4*)&w0[tid * 4 + i * 1024];
  for (int i = tid; i < 352; i += 256)        // 1408 floats = 352 float4
    *(float4*)&wds[i * 4] = *(const float4*)&wd[i * 4];

  const int lane = tid & 63;
  const int wv = tid >> 6;
  const int d = lane;
  const float a_sc = bn_a_gamma[d] * rsqrtf(bn_a_var[d] + kEps);
  const float a_m = bn_a_mean[d], a_b = bn_a_beta[d];
  const float s1a = bn1_gamma[d] * rsqrtf(bn1_var[d] + kEps);
  const float m1a = bn1_mean[d], bb1a = bn1_beta[d];
  const float s1b = bn1_gamma[d + 64] * rsqrtf(bn1_var[d + 64] + kEps);
  const float m1b = bn1_mean[d + 64], bb1b = bn1_beta[d + 64];
  const float b0v = b0[d];
  const float bdv = (d < NCLS) ? bd[d] : 0.f;
  __syncthreads();

  const int r0 = blockIdx.x * 32 + wv * 8;
  for (int i = 0; i < 8; ++i) {
    const size_t r = r0 + i;
    const float x1v = x1[r * DD + d];
    const float xa = (x1v - a_m) * a_sc + a_b;
    __syncthreads();                          // WAR from prev iter
    xsh[wv][d] = xa;
    __syncthreads();
    float acc = b0v;
#pragma unroll 8
    for (int e = 0; e < 64; ++e) acc += xsh[wv][e] * w0s[e * 64 + d];
    const float h1 = (fmaxf(acc, 0.f) - m1a) * s1a + bb1a;
    const float o2v = o2m[r * DD + d];
    const float h2 = (o2v - m1b) * s1b + bb1b;
    hsh[wv][d] = h1;
    hsh[wv][64 + d] = h2;
    __syncthreads();
    float lg = 0.f;
    if (d < NCLS) {
      lg = bdv;
#pragma unroll 8
      for (int e = 0; e < 128; ++e) lg += hsh[wv][e] * wds[e * NCLS + d];
      lsh[wv][d] = lg;
    }
    __syncthreads();
    if (d < NCLS) {
      float mx = lsh[wv][0];
#pragma unroll
      for (int c = 1; c < NCLS; ++c) mx = fmaxf(mx, lsh[wv][c]);
      float ssum = 0.f;
#pragma unroll
      for (int c = 0; c < NCLS; ++c) ssum += __expf(lsh[wv][c] - mx);
      out[r * NCLS + d] = __expf(lg - mx) / ssum;
    }
  }
}

// -----------------------------------------------------------------------
extern "C" void kernel_launch(void* const* d_in, const int* in_sizes, int n_in,
                              void* d_out, int out_size, void* d_ws, size_t ws_size,
                              hipStream_t stream) {
  (void)in_sizes; (void)n_in; (void)out_size;
  const float* x  = (const float*)d_in[0];
  const float* wq = (const float*)d_in[1];
  const float* wk = (const float*)d_in[2];
  const float* wv = (const float*)d_in[3];
  const float* bn_a_gamma = (const float*)d_in[4];
  const float* bn_a_beta  = (const float*)d_in[5];
  const float* bn_a_mean  = (const float*)d_in[6];
  const float* bn_a_var   = (const float*)d_in[7];
  const float* w0 = (const float*)d_in[8];
  const float* b0 = (const float*)d_in[9];
  const float* w1 = (const float*)d_in[10];
  const float* b1 = (const float*)d_in[11];
  const float* bn1_gamma = (const float*)d_in[12];
  const float* bn1_beta  = (const float*)d_in[13];
  const float* bn1_mean  = (const float*)d_in[14];
  const float* bn1_var   = (const float*)d_in[15];
  const float* wd = (const float*)d_in[16];
  const float* bd = (const float*)d_in[17];
  float* out = (float*)d_out;

  float* w = (float*)d_ws;
  float* pe = w;  w += (size_t)TT * FF;
  float* q  = w;  w += (size_t)M * DD;
  float* k  = w;  w += (size_t)M * DD;
  float* v  = w;  w += (size_t)M * DD;
  float* o2 = w;  w += (size_t)M * DD;
  float* x1 = w;  w += (size_t)M * DD;
  const size_t used = (size_t)(w - (float*)d_ws);
  const size_t avail = ws_size / sizeof(float);
  int S = 4;
  while (S > 1 && used + (size_t)S * ((size_t)M * DD + M) > avail) S >>= 1;
  float* po = w;
  float* pl = po + (size_t)S * M * DD;

  pe_kernel<<<dim3(TT * FF / 256), dim3(256), 0, stream>>>(pe);
  proj_kernel<<<dim3(M / 64, 4), dim3(256), 0, stream>>>(
      x, pe, wq, wk, wv, w1, b1, q, k, v, o2);
  attn_kernel<<<dim3(TT / 256, BB, S), dim3(256), 0, stream>>>(
      q, k, v, po, pl, 16 / S);
  combine_kernel<<<dim3(M * DD / 256), dim3(256), 0, stream>>>(po, pl, x1, S);
  head_kernel<<<dim3(M / 32), dim3(256), 0, stream>>>(
      x1, o2, bn_a_gamma, bn_a_beta, bn_a_mean, bn_a_var,
      w0, b0, bn1_gamma, bn1_beta, bn1_mean, bn1_var, wd, bd, out);
}

// Round 2
// 129.648 us; speedup vs baseline: 2.8880x; 2.8880x over previous
//
#include <hip/hip_runtime.h>
#include <math.h>

#define BB 32
#define TT 1024
#define FF 128
#define DD 64
#define NCLS 11
constexpr float kEps = 1e-3f;
constexpr int M = BB * TT;  // 32768 rows

typedef __attribute__((ext_vector_type(8))) short short8v;
typedef __attribute__((ext_vector_type(4))) short short4v;
typedef __attribute__((ext_vector_type(4))) float float4v;

__device__ __forceinline__ short f2bf(float f) {
  union { float f; unsigned u; } v; v.f = f;
  return (short)((v.u + 0x7FFFu + ((v.u >> 16) & 1u)) >> 16);
}
__device__ __forceinline__ float bf2f(short s) {
  union { unsigned u; float f; } v; v.u = ((unsigned)(unsigned short)s) << 16;
  return v.f;
}

// ---------------------------------------------------------------- PE table
__global__ __launch_bounds__(256) void pe_kernel(float* __restrict__ pe) {
  int idx = blockIdx.x * 256 + threadIdx.x;          // 131072 total
  int t = idx >> 7, f = idx & 127;
  float div = expf(-logf(10000.0f) * (float)(f & ~1) / (float)FF);
  float ang = (float)t * div;
  pe[idx] = (f & 1) ? cosf(ang) : sinf(ang);
}

// ------------------------------------------- QKV + out2 projections (fp32 math, bf16 out)
// grid: (M/64, 4). y=0,1,2 -> q,k,v from (x+pe); y=3 -> relu(x@w1+b1)
// v is stored TRANSPOSED per batch: vt[b][d][t]
__global__ __launch_bounds__(256) void proj_kernel(
    const float* __restrict__ x, const float* __restrict__ pe,
    const float* __restrict__ wq, const float* __restrict__ wk,
    const float* __restrict__ wv, const float* __restrict__ w1,
    const float* __restrict__ b1,
    short* __restrict__ qo, short* __restrict__ ko,
    short* __restrict__ vt, short* __restrict__ o2) {
  __shared__ float xs[64][132];       // pad 132: 2-way conflicts only
  __shared__ float wsh[64 * 64];      // half of W at a time
  const int tid = threadIdx.x;
  const int r0 = blockIdx.x * 64;
  const int y = blockIdx.y;
  const float* w = (y == 0) ? wq : (y == 1) ? wk : (y == 2) ? wv : w1;
  const bool addpe = (y < 3);

#pragma unroll
  for (int i = 0; i < 8; ++i) {
    int idx = tid * 4 + i * 1024;     // 8192 floats
    int lr = idx >> 7, f = idx & 127;
    float4 xv = *(const float4*)&x[(size_t)(r0 + lr) * FF + f];
    if (addpe) {
      int t = (r0 + lr) & (TT - 1);
      const float4 pv = *(const float4*)&pe[t * FF + f];
      xv.x += pv.x; xv.y += pv.y; xv.z += pv.z; xv.w += pv.w;
    }
    *(float4*)&xs[lr][f] = xv;
  }

  const int tx = tid & 15, ty = tid >> 4;
  const int c0 = tx * 4, rr = ty * 4;
  float acc[4][4] = {};

  for (int half = 0; half < 2; ++half) {
    __syncthreads();
#pragma unroll
    for (int i = 0; i < 4; ++i) {
      int idx = tid * 4 + i * 1024;
      *(float4*)&wsh[idx] = *(const float4*)&w[half * 4096 + idx];
    }
    __syncthreads();
#pragma unroll 4
    for (int kk = 0; kk < 64; kk += 4) {
      float4 a[4], b[4];
#pragma unroll
      for (int i = 0; i < 4; ++i) a[i] = *(const float4*)&xs[rr + i][half * 64 + kk];
#pragma unroll
      for (int j = 0; j < 4; ++j) b[j] = *(const float4*)&wsh[(kk + j) * 64 + c0];
#pragma unroll
      for (int i = 0; i < 4; ++i) {
        const float av[4] = {a[i].x, a[i].y, a[i].z, a[i].w};
#pragma unroll
        for (int j = 0; j < 4; ++j) {
          acc[i][0] += av[j] * b[j].x;
          acc[i][1] += av[j] * b[j].y;
          acc[i][2] += av[j] * b[j].z;
          acc[i][3] += av[j] * b[j].w;
        }
      }
    }
  }

  if (y == 2) {
    // transposed store: vt[b][c][t], 4 consecutive t per col
    const int b = r0 >> 10;
    const int t0 = (r0 & 1023) + rr;
#pragma unroll
    for (int j = 0; j < 4; ++j) {
      short4v s;
      s[0] = f2bf(acc[0][j]); s[1] = f2bf(acc[1][j]);
      s[2] = f2bf(acc[2][j]); s[3] = f2bf(acc[3][j]);
      *(short4v*)&vt[((size_t)(b * DD + c0 + j)) * TT + t0] = s;
    }
  } else {
    short* dst = (y == 0) ? qo : (y == 1) ? ko : o2;
#pragma unroll
    for (int i = 0; i < 4; ++i) {
      float o4[4] = {acc[i][0], acc[i][1], acc[i][2], acc[i][3]};
      if (y == 3) {
        const float4 bv = *(const float4*)&b1[c0];
        o4[0] = fmaxf(o4[0] + bv.x, 0.f);
        o4[1] = fmaxf(o4[1] + bv.y, 0.f);
        o4[2] = fmaxf(o4[2] + bv.z, 0.f);
        o4[3] = fmaxf(o4[3] + bv.w, 0.f);
      }
      short4v s;
      s[0] = f2bf(o4[0]); s[1] = f2bf(o4[1]); s[2] = f2bf(o4[2]); s[3] = f2bf(o4[3]);
      *(short4v*)&dst[(size_t)(r0 + rr + i) * DD + c0] = s;
    }
  }
}

// ------------------------------------------------ MFMA flash attention (bf16)
// grid: (T/64, B, S). 4 waves/block, wave = 16 q-rows. KVBLK=64.
// No max-shift (scores ~N(0,0.33)); K-split partials are plain sums.
// LDS tiles XOR-swizzled: short_idx ^= (row&7)<<3  (== byte ^ (row&7)<<4)
__global__ __launch_bounds__(256) void attn_kernel(
    const short* __restrict__ qg, const short* __restrict__ kg,
    const short* __restrict__ vtg, float* __restrict__ po,
    float* __restrict__ pl, int ktiles) {
  __shared__ __align__(16) short Ks[64 * 64];      // [kv][d]
  __shared__ __align__(16) short Vs[64 * 64];      // [d][kv]
  __shared__ __align__(16) short Ps[4 * 16 * 64];  // per-wave [i][j]
  const int tid = threadIdx.x;
  const int lane = tid & 63;
  const int wv = tid >> 6;
  const int b = blockIdx.y;
  const int sidx = blockIdx.z;
  const int qx = blockIdx.x;
  const int l15 = lane & 15;
  const int lg = lane >> 4;          // 0..3
  const int qbase = qx * 64 + wv * 16;

  // Q fragments: A[m=l15][k=d], 8 consecutive d per lane-group
  short8v qf[2];
#pragma unroll
  for (int dt = 0; dt < 2; ++dt) {
    const size_t off = ((size_t)(b * TT + qbase + l15)) * DD + dt * 32 + lg * 8;
    qf[dt] = *(const short8v*)&qg[off];
  }
  float4v oacc[4];
#pragma unroll
  for (int dt = 0; dt < 4; ++dt) oacc[dt] = (float4v)0.0f;
  float lacc[4] = {0.f, 0.f, 0.f, 0.f};

  const int kt0 = sidx * ktiles;
  const int pbase = wv * 1024;
  for (int kt = kt0; kt < kt0 + ktiles; ++kt) {
    __syncthreads();                 // protect prev tile reads
#pragma unroll
    for (int p = 0; p < 2; ++p) {
      int idx = tid + p * 256;       // 0..511
      int row = idx >> 3, c8 = (idx & 7) * 8;
      int sw = c8 ^ ((row & 7) << 3);
      int4 kv = *(const int4*)&kg[((size_t)(b * TT + kt * 64 + row)) * DD + c8];
      *(int4*)&Ks[row * 64 + sw] = kv;
      int4 vv = *(const int4*)&vtg[((size_t)(b * DD + row)) * TT + kt * 64 + c8];
      *(int4*)&Vs[row * 64 + sw] = vv;
    }
    __syncthreads();

    // QK^T -> exp -> P (wave-private LDS)
#pragma unroll
    for (int jt = 0; jt < 4; ++jt) {
      float4v s = {0.f, 0.f, 0.f, 0.f};
      const int j = jt * 16 + l15;
#pragma unroll
      for (int dt = 0; dt < 2; ++dt) {
        const int d0 = dt * 32 + lg * 8;
        short8v kf = *(const short8v*)&Ks[j * 64 + (d0 ^ ((j & 7) << 3))];
        s = __builtin_amdgcn_mfma_f32_16x16x32_bf16(qf[dt], kf, s, 0, 0, 0);
      }
#pragma unroll
      for (int r = 0; r < 4; ++r) {
        float pv = __expf(s[r] * 0.125f);
        lacc[r] += pv;
        const int i = lg * 4 + r;
        Ps[pbase + i * 64 + (j ^ ((i & 7) << 3))] = f2bf(pv);
      }
    }

    // PV: A = P frags, B = Vt frags
    short8v pf[2];
#pragma unroll
    for (int jc = 0; jc < 2; ++jc) {
      const int j0 = jc * 32 + lg * 8;
      pf[jc] = *(const short8v*)&Ps[pbase + l15 * 64 + (j0 ^ ((l15 & 7) << 3))];
    }
#pragma unroll
    for (int dt = 0; dt < 4; ++dt) {
      const int d = dt * 16 + l15;
#pragma unroll
      for (int jc = 0; jc < 2; ++jc) {
        const int j0 = jc * 32 + lg * 8;
        short8v vf = *(const short8v*)&Vs[d * 64 + (j0 ^ ((d & 7) << 3))];
        oacc[dt] = __builtin_amdgcn_mfma_f32_16x16x32_bf16(pf[jc], vf, oacc[dt], 0, 0, 0);
      }
    }
  }

  // reduce row-sums across the 16-lane group
#pragma unroll
  for (int off = 1; off < 16; off <<= 1) {
#pragma unroll
    for (int r = 0; r < 4; ++r) lacc[r] += __shfl_xor(lacc[r], off);
  }

  const size_t growb = (size_t)b * TT + qbase + lg * 4;
#pragma unroll
  for (int r = 0; r < 4; ++r) {
    const size_t obase = ((size_t)sidx * M + growb + r) * DD;
#pragma unroll
    for (int dt = 0; dt < 4; ++dt)
      po[obase + dt * 16 + l15] = oacc[dt][r];
  }
#pragma unroll
  for (int r = 0; r < 4; ++r)
    if (l15 == r) pl[(size_t)sidx * M + growb + r] = lacc[r];
}

// ---------------------------------------------------- combine K-split parts
__global__ __launch_bounds__(256) void combine_kernel(
    const float* __restrict__ po, const float* __restrict__ pl,
    float* __restrict__ x1, int S) {
  const int idx = blockIdx.x * 256 + threadIdx.x;    // M*DD total
  const int row = idx >> 6;
  float l = 0.f;
  for (int s = 0; s < S; ++s) l += pl[(size_t)s * M + row];
  float acc = 0.f;
  for (int s = 0; s < S; ++s) acc += po[(size_t)s * M * DD + idx];
  x1[idx] = acc / l;
}

// ----------------- bn_a -> out1 -> concat -> bn1 -> logits -> softmax
__global__ __launch_bounds__(256) void head_kernel(
    const float* __restrict__ x1, const short* __restrict__ o2m,
    const float* __restrict__ bn_a_gamma, const float* __restrict__ bn_a_beta,
    const float* __restrict__ bn_a_mean, const float* __restrict__ bn_a_var,
    const float* __restrict__ w0, const float* __restrict__ b0,
    const float* __restrict__ bn1_gamma, const float* __restrict__ bn1_beta,
    const float* __restrict__ bn1_mean, const float* __restrict__ bn1_var,
    const float* __restrict__ wd, const float* __restrict__ bd,
    float* __restrict__ out) {
  __shared__ float w0s[64 * 64];
  __shared__ float wds[128 * NCLS];
  __shared__ float xsh[4][64];
  __shared__ float hsh[4][128];
  __shared__ float lsh[4][16];
  const int tid = threadIdx.x;
#pragma unroll
  for (int i = 0; i < 4; ++i)
    *(float4*)&w0s[tid * 4 + i * 1024] = *(const float4*)&w0[tid * 4 + i * 1024];
  for (int i = tid; i < 352; i += 256)
    *(float4*)&wds[i * 4] = *(const float4*)&wd[i * 4];

  const int lane = tid & 63;
  const int wv = tid >> 6;
  const int d = lane;
  const float a_sc = bn_a_gamma[d] * rsqrtf(bn_a_var[d] + kEps);
  const float a_m = bn_a_mean[d], a_b = bn_a_beta[d];
  const float s1a = bn1_gamma[d] * rsqrtf(bn1_var[d] + kEps);
  const float m1a = bn1_mean[d], bb1a = bn1_beta[d];
  const float s1b = bn1_gamma[d + 64] * rsqrtf(bn1_var[d + 64] + kEps);
  const float m1b = bn1_mean[d + 64], bb1b = bn1_beta[d + 64];
  const float b0v = b0[d];
  const float bdv = (d < NCLS) ? bd[d] : 0.f;
  __syncthreads();

  const int r0 = blockIdx.x * 32 + wv * 8;
  for (int i = 0; i < 8; ++i) {
    const size_t r = r0 + i;
    const float x1v = x1[r * DD + d];
    const float xa = (x1v - a_m) * a_sc + a_b;
    __syncthreads();
    xsh[wv][d] = xa;
    __syncthreads();
    float acc = b0v;
#pragma unroll 8
    for (int e = 0; e < 64; ++e) acc += xsh[wv][e] * w0s[e * 64 + d];
    const float h1 = (fmaxf(acc, 0.f) - m1a) * s1a + bb1a;
    const float o2v = bf2f(o2m[r * DD + d]);
    const float h2 = (o2v - m1b) * s1b + bb1b;
    hsh[wv][d] = h1;
    hsh[wv][64 + d] = h2;
    __syncthreads();
    float lg = 0.f;
    if (d < NCLS) {
      lg = bdv;
#pragma unroll 8
      for (int e = 0; e < 128; ++e) lg += hsh[wv][e] * wds[e * NCLS + d];
      lsh[wv][d] = lg;
    }
    __syncthreads();
    if (d < NCLS) {
      float mx = lsh[wv][0];
#pragma unroll
      for (int c = 1; c < NCLS; ++c) mx = fmaxf(mx, lsh[wv][c]);
      float ssum = 0.f;
#pragma unroll
      for (int c = 0; c < NCLS; ++c) ssum += __expf(lsh[wv][c] - mx);
      out[r * NCLS + d] = __expf(lg - mx) / ssum;
    }
  }
}

// -----------------------------------------------------------------------
extern "C" void kernel_launch(void* const* d_in, const int* in_sizes, int n_in,
                              void* d_out, int out_size, void* d_ws, size_t ws_size,
                              hipStream_t stream) {
  (void)in_sizes; (void)n_in; (void)out_size;
  const float* x  = (const float*)d_in[0];
  const float* wq = (const float*)d_in[1];
  const float* wk = (const float*)d_in[2];
  const float* wv = (const float*)d_in[3];
  const float* bn_a_gamma = (const float*)d_in[4];
  const float* bn_a_beta  = (const float*)d_in[5];
  const float* bn_a_mean  = (const float*)d_in[6];
  const float* bn_a_var   = (const float*)d_in[7];
  const float* w0 = (const float*)d_in[8];
  const float* b0 = (const float*)d_in[9];
  const float* w1 = (const float*)d_in[10];
  const float* b1 = (const float*)d_in[11];
  const float* bn1_gamma = (const float*)d_in[12];
  const float* bn1_beta  = (const float*)d_in[13];
  const float* bn1_mean  = (const float*)d_in[14];
  const float* bn1_var   = (const float*)d_in[15];
  const float* wd = (const float*)d_in[16];
  const float* bd = (const float*)d_in[17];
  float* out = (float*)d_out;

  char* cur = (char*)d_ws;
  float* pe = (float*)cur; cur += (size_t)TT * FF * 4;
  short* q  = (short*)cur; cur += (size_t)M * DD * 2;
  short* k  = (short*)cur; cur += (size_t)M * DD * 2;
  short* vt = (short*)cur; cur += (size_t)M * DD * 2;
  short* o2 = (short*)cur; cur += (size_t)M * DD * 2;
  float* x1 = (float*)cur; cur += (size_t)M * DD * 4;
  const size_t used = (size_t)(cur - (char*)d_ws);
  int S = 2;
  while (S > 1 && used + (size_t)S * ((size_t)M * DD + M) * 4 > ws_size) S >>= 1;
  float* po = (float*)cur;
  float* pl = po + (size_t)S * M * DD;

  pe_kernel<<<dim3(TT * FF / 256), dim3(256), 0, stream>>>(pe);
  proj_kernel<<<dim3(M / 64, 4), dim3(256), 0, stream>>>(
      x, pe, wq, wk, wv, w1, b1, q, k, vt, o2);
  attn_kernel<<<dim3(TT / 64, BB, S), dim3(256), 0, stream>>>(
      q, k, vt, po, pl, 16 / S);
  combine_kernel<<<dim3(M * DD / 256), dim3(256), 0, stream>>>(po, pl, x1, S);
  head_kernel<<<dim3(M / 32), dim3(256), 0, stream>>>(
      x1, o2, bn_a_gamma, bn_a_beta, bn_a_mean, bn_a_var,
      w0, b0, bn1_gamma, bn1_beta, bn1_mean, bn1_var, wd, bd, out);
}

// Round 3
// 109.602 us; speedup vs baseline: 3.4162x; 1.1829x over previous
//
#include <hip/hip_runtime.h>
#include <math.h>

#define BB 32
#define TT 1024
#define FF 128
#define DD 64
#define NCLS 11
constexpr float kEps = 1e-3f;
constexpr int M = BB * TT;  // 32768 rows

typedef __attribute__((ext_vector_type(8))) short short8v;
typedef __attribute__((ext_vector_type(4))) short short4v;
typedef __attribute__((ext_vector_type(4))) float float4v;

__device__ __forceinline__ short f2bf(float f) {
  union { float f; unsigned u; } v; v.f = f;
  return (short)((v.u + 0x7FFFu + ((v.u >> 16) & 1u)) >> 16);
}
__device__ __forceinline__ float bf2f(short s) {
  union { unsigned u; float f; } v; v.u = ((unsigned)(unsigned short)s) << 16;
  return v.f;
}

// ---------------------------------------------------------------- PE table
__global__ __launch_bounds__(256) void pe_kernel(float* __restrict__ pe) {
  int idx = blockIdx.x * 256 + threadIdx.x;          // 131072 total
  int t = idx >> 7, f = idx & 127;
  float div = expf(-logf(10000.0f) * (float)(f & ~1) / (float)FF);
  float ang = (float)t * div;
  pe[idx] = (f & 1) ? cosf(ang) : sinf(ang);
}

// --------------------------------- QKV + out2 projections (bf16 MFMA)
// grid: (M/128, 4). y=0,1,2 -> q,k,v from (x+pe); y=3 -> relu(x@w1+b1)
// y==2 (v): natural orientation, stores transposed vt[b][d][t].
// y!=2: swapped orientation (C^T), stores row-major [row][d].
__global__ __launch_bounds__(256) void proj_kernel(
    const float* __restrict__ x, const float* __restrict__ pe,
    const float* __restrict__ wq, const float* __restrict__ wk,
    const float* __restrict__ wv, const float* __restrict__ w1,
    const float* __restrict__ b1,
    short* __restrict__ qo, short* __restrict__ ko,
    short* __restrict__ vt, short* __restrict__ o2) {
  __shared__ __align__(16) short xs[128 * 128];   // [row][k], chunk-swizzled
  __shared__ __align__(16) short wTs[64 * 128];   // [n][k], chunk-swizzled
  const int tid = threadIdx.x;
  const int lane = tid & 63;
  const int wv4 = tid >> 6;          // wave 0..3
  const int l15 = lane & 15;
  const int lg = lane >> 4;          // 0..3
  const int r0 = blockIdx.x * 128;
  const int y = blockIdx.y;
  const float* w = (y == 0) ? wq : (y == 1) ? wk : (y == 2) ? wv : w1;
  const bool addpe = (y < 3);

  // stage x (+pe) -> bf16 LDS, swizzled 16B chunks
#pragma unroll
  for (int i = 0; i < 8; ++i) {
    int id = tid + i * 256;          // 0..2047
    int row = id >> 4, chunk = id & 15;
    const float* xp = &x[((size_t)(r0 + row)) * FF + chunk * 8];
    float4 a = *(const float4*)xp;
    float4 b = *(const float4*)(xp + 4);
    if (addpe) {
      const float* pp = &pe[((r0 & 1023) + row) * FF + chunk * 8];
      const float4 pa = *(const float4*)pp;
      const float4 pb = *(const float4*)(pp + 4);
      a.x += pa.x; a.y += pa.y; a.z += pa.z; a.w += pa.w;
      b.x += pb.x; b.y += pb.y; b.z += pb.z; b.w += pb.w;
    }
    short8v s8;
    s8[0] = f2bf(a.x); s8[1] = f2bf(a.y); s8[2] = f2bf(a.z); s8[3] = f2bf(a.w);
    s8[4] = f2bf(b.x); s8[5] = f2bf(b.y); s8[6] = f2bf(b.z); s8[7] = f2bf(b.w);
    *(short8v*)&xs[row * 128 + ((chunk ^ (row & 7)) << 3)] = s8;
  }

  // stage w^T -> bf16 LDS (w is [128][64] row-major)
#pragma unroll
  for (int i = 0; i < 8; ++i) {
    int id = tid + i * 256;          // 0..2047
    int k = id >> 4, nq = id & 15;
    const float4 w4 = *(const float4*)&w[k * 64 + nq * 4];
    const float wvals[4] = {w4.x, w4.y, w4.z, w4.w};
#pragma unroll
    for (int j = 0; j < 4; ++j) {
      int n = nq * 4 + j;
      wTs[n * 128 + (((k >> 3) ^ (n & 7)) << 3) + (k & 7)] = f2bf(wvals[j]);
    }
  }
  __syncthreads();

  float4v acc[2][4];
#pragma unroll
  for (int rt = 0; rt < 2; ++rt)
#pragma unroll
    for (int dt = 0; dt < 4; ++dt) acc[rt][dt] = (float4v)0.0f;

  const bool natural = (y == 2);
#pragma unroll
  for (int kt = 0; kt < 4; ++kt) {
    const int chunk = kt * 4 + lg;
    short8v xa[2], wa[4];
#pragma unroll
    for (int rt = 0; rt < 2; ++rt) {
      const int row = wv4 * 32 + rt * 16 + l15;
      xa[rt] = *(const short8v*)&xs[row * 128 + ((chunk ^ (row & 7)) << 3)];
    }
#pragma unroll
    for (int dt = 0; dt < 4; ++dt) {
      const int n = dt * 16 + l15;
      wa[dt] = *(const short8v*)&wTs[n * 128 + ((chunk ^ (n & 7)) << 3)];
    }
#pragma unroll
    for (int rt = 0; rt < 2; ++rt)
#pragma unroll
      for (int dt = 0; dt < 4; ++dt)
        acc[rt][dt] = natural
            ? __builtin_amdgcn_mfma_f32_16x16x32_bf16(xa[rt], wa[dt], acc[rt][dt], 0, 0, 0)
            : __builtin_amdgcn_mfma_f32_16x16x32_bf16(wa[dt], xa[rt], acc[rt][dt], 0, 0, 0);
  }

  if (natural) {
    // D[m=row][n=d]: lane holds 4 consecutive t (regs) for fixed d
    const int bq = r0 >> 10;
    const int tb = (r0 & 1023) + wv4 * 32;
#pragma unroll
    for (int rt = 0; rt < 2; ++rt) {
#pragma unroll
      for (int dt = 0; dt < 4; ++dt) {
        const int d = dt * 16 + l15;
        const int t0 = tb + rt * 16 + lg * 4;
        short4v s;
#pragma unroll
        for (int r = 0; r < 4; ++r) s[r] = f2bf(acc[rt][dt][r]);
        *(short4v*)&vt[((size_t)(bq * DD + d)) * TT + t0] = s;
      }
    }
  } else {
    // D^T[m=d][n=row]: lane holds 4 consecutive d (regs) for fixed row
    short* dst = (y == 0) ? qo : (y == 1) ? ko : o2;
#pragma unroll
    for (int rt = 0; rt < 2; ++rt) {
      const int row = r0 + wv4 * 32 + rt * 16 + l15;
#pragma unroll
      for (int dt = 0; dt < 4; ++dt) {
        const int d0 = dt * 16 + lg * 4;
        float v0 = acc[rt][dt][0], v1 = acc[rt][dt][1];
        float v2 = acc[rt][dt][2], v3 = acc[rt][dt][3];
        if (y == 3) {
          const float4 bv = *(const float4*)&b1[d0];
          v0 = fmaxf(v0 + bv.x, 0.f); v1 = fmaxf(v1 + bv.y, 0.f);
          v2 = fmaxf(v2 + bv.z, 0.f); v3 = fmaxf(v3 + bv.w, 0.f);
        }
        short4v s;
        s[0] = f2bf(v0); s[1] = f2bf(v1); s[2] = f2bf(v2); s[3] = f2bf(v3);
        *(short4v*)&dst[(size_t)row * DD + d0] = s;
      }
    }
  }
}

// ------------------------------------------------ MFMA flash attention (bf16)
// grid: (T/64, B, S). 4 waves/block, wave = 16 q-rows. KVBLK=64.
// No max-shift (scores ~N(0,0.33)); K-split partials are plain sums.
__global__ __launch_bounds__(256) void attn_kernel(
    const short* __restrict__ qg, const short* __restrict__ kg,
    const short* __restrict__ vtg, float* __restrict__ po,
    float* __restrict__ pl, int ktiles) {
  __shared__ __align__(16) short Ks[64 * 64];      // [kv][d]
  __shared__ __align__(16) short Vs[64 * 64];      // [d][kv]
  __shared__ __align__(16) short Ps[4 * 16 * 64];  // per-wave [i][j]
  const int tid = threadIdx.x;
  const int lane = tid & 63;
  const int wv = tid >> 6;
  const int b = blockIdx.y;
  const int sidx = blockIdx.z;
  const int qx = blockIdx.x;
  const int l15 = lane & 15;
  const int lg = lane >> 4;          // 0..3
  const int qbase = qx * 64 + wv * 16;

  short8v qf[2];
#pragma unroll
  for (int dt = 0; dt < 2; ++dt) {
    const size_t off = ((size_t)(b * TT + qbase + l15)) * DD + dt * 32 + lg * 8;
    qf[dt] = *(const short8v*)&qg[off];
  }
  float4v oacc[4];
#pragma unroll
  for (int dt = 0; dt < 4; ++dt) oacc[dt] = (float4v)0.0f;
  float lacc[4] = {0.f, 0.f, 0.f, 0.f};

  const int kt0 = sidx * ktiles;
  const int pbase = wv * 1024;
  for (int kt = kt0; kt < kt0 + ktiles; ++kt) {
    __syncthreads();
#pragma unroll
    for (int p = 0; p < 2; ++p) {
      int idx = tid + p * 256;       // 0..511
      int row = idx >> 3, c8 = (idx & 7) * 8;
      int sw = c8 ^ ((row & 7) << 3);
      int4 kv = *(const int4*)&kg[((size_t)(b * TT + kt * 64 + row)) * DD + c8];
      *(int4*)&Ks[row * 64 + sw] = kv;
      int4 vv = *(const int4*)&vtg[((size_t)(b * DD + row)) * TT + kt * 64 + c8];
      *(int4*)&Vs[row * 64 + sw] = vv;
    }
    __syncthreads();

#pragma unroll
    for (int jt = 0; jt < 4; ++jt) {
      float4v s = {0.f, 0.f, 0.f, 0.f};
      const int j = jt * 16 + l15;
#pragma unroll
      for (int dt = 0; dt < 2; ++dt) {
        const int d0 = dt * 32 + lg * 8;
        short8v kf = *(const short8v*)&Ks[j * 64 + (d0 ^ ((j & 7) << 3))];
        s = __builtin_amdgcn_mfma_f32_16x16x32_bf16(qf[dt], kf, s, 0, 0, 0);
      }
#pragma unroll
      for (int r = 0; r < 4; ++r) {
        float pv = __expf(s[r] * 0.125f);
        lacc[r] += pv;
        const int i = lg * 4 + r;
        Ps[pbase + i * 64 + (j ^ ((i & 7) << 3))] = f2bf(pv);
      }
    }

    short8v pf[2];
#pragma unroll
    for (int jc = 0; jc < 2; ++jc) {
      const int j0 = jc * 32 + lg * 8;
      pf[jc] = *(const short8v*)&Ps[pbase + l15 * 64 + (j0 ^ ((l15 & 7) << 3))];
    }
#pragma unroll
    for (int dt = 0; dt < 4; ++dt) {
      const int d = dt * 16 + l15;
#pragma unroll
      for (int jc = 0; jc < 2; ++jc) {
        const int j0 = jc * 32 + lg * 8;
        short8v vf = *(const short8v*)&Vs[d * 64 + (j0 ^ ((d & 7) << 3))];
        oacc[dt] = __builtin_amdgcn_mfma_f32_16x16x32_bf16(pf[jc], vf, oacc[dt], 0, 0, 0);
      }
    }
  }

#pragma unroll
  for (int off = 1; off < 16; off <<= 1) {
#pragma unroll
    for (int r = 0; r < 4; ++r) lacc[r] += __shfl_xor(lacc[r], off);
  }

  const size_t growb = (size_t)b * TT + qbase + lg * 4;
#pragma unroll
  for (int r = 0; r < 4; ++r) {
    const size_t obase = ((size_t)sidx * M + growb + r) * DD;
#pragma unroll
    for (int dt = 0; dt < 4; ++dt)
      po[obase + dt * 16 + l15] = oacc[dt][r];
  }
#pragma unroll
  for (int r = 0; r < 4; ++r)
    if (l15 == r) pl[(size_t)sidx * M + growb + r] = lacc[r];
}

// ---------------------------------------------------- combine K-split parts
__global__ __launch_bounds__(256) void combine_kernel(
    const float* __restrict__ po, const float* __restrict__ pl,
    float* __restrict__ x1, int S) {
  const int idx = blockIdx.x * 256 + threadIdx.x;    // M*DD total
  const int row = idx >> 6;
  float l = 0.f;
  for (int s = 0; s < S; ++s) l += pl[(size_t)s * M + row];
  float acc = 0.f;
  for (int s = 0; s < S; ++s) acc += po[(size_t)s * M * DD + idx];
  x1[idx] = acc / l;
}

// ----------------- bn_a -> out1 -> concat -> bn1 -> logits -> softmax
__global__ __launch_bounds__(256) void head_kernel(
    const float* __restrict__ x1, const short* __restrict__ o2m,
    const float* __restrict__ bn_a_gamma, const float* __restrict__ bn_a_beta,
    const float* __restrict__ bn_a_mean, const float* __restrict__ bn_a_var,
    const float* __restrict__ w0, const float* __restrict__ b0,
    const float* __restrict__ bn1_gamma, const float* __restrict__ bn1_beta,
    const float* __restrict__ bn1_mean, const float* __restrict__ bn1_var,
    const float* __restrict__ wd, const float* __restrict__ bd,
    float* __restrict__ out) {
  __shared__ float w0s[64 * 64];
  __shared__ float wds[128 * NCLS];
  __shared__ float xsh[4][64];
  __shared__ float hsh[4][128];
  __shared__ float lsh[4][16];
  const int tid = threadIdx.x;
#pragma unroll
  for (int i = 0; i < 4; ++i)
    *(float4*)&w0s[tid * 4 + i * 1024] = *(const float4*)&w0[tid * 4 + i * 1024];
  for (int i = tid; i < 352; i += 256)
    *(float4*)&wds[i * 4] = *(const float4*)&wd[i * 4];

  const int lane = tid & 63;
  const int wv = tid >> 6;
  const int d = lane;
  const float a_sc = bn_a_gamma[d] * rsqrtf(bn_a_var[d] + kEps);
  const float a_m = bn_a_mean[d], a_b = bn_a_beta[d];
  const float s1a = bn1_gamma[d] * rsqrtf(bn1_var[d] + kEps);
  const float m1a = bn1_mean[d], bb1a = bn1_beta[d];
  const float s1b = bn1_gamma[d + 64] * rsqrtf(bn1_var[d + 64] + kEps);
  const float m1b = bn1_mean[d + 64], bb1b = bn1_beta[d + 64];
  const float b0v = b0[d];
  const float bdv = (d < NCLS) ? bd[d] : 0.f;
  __syncthreads();

  const int r0 = blockIdx.x * 32 + wv * 8;
  for (int i = 0; i < 8; ++i) {
    const size_t r = r0 + i;
    const float x1v = x1[r * DD + d];
    const float xa = (x1v - a_m) * a_sc + a_b;
    __syncthreads();
    xsh[wv][d] = xa;
    __syncthreads();
    float acc = b0v;
#pragma unroll 8
    for (int e = 0; e < 64; ++e) acc += xsh[wv][e] * w0s[e * 64 + d];
    const float h1 = (fmaxf(acc, 0.f) - m1a) * s1a + bb1a;
    const float o2v = bf2f(o2m[r * DD + d]);
    const float h2 = (o2v - m1b) * s1b + bb1b;
    hsh[wv][d] = h1;
    hsh[wv][64 + d] = h2;
    __syncthreads();
    float lg = 0.f;
    if (d < NCLS) {
      lg = bdv;
#pragma unroll 8
      for (int e = 0; e < 128; ++e) lg += hsh[wv][e] * wds[e * NCLS + d];
      lsh[wv][d] = lg;
    }
    __syncthreads();
    if (d < NCLS) {
      float mx = lsh[wv][0];
#pragma unroll
      for (int c = 1; c < NCLS; ++c) mx = fmaxf(mx, lsh[wv][c]);
      float ssum = 0.f;
#pragma unroll
      for (int c = 0; c < NCLS; ++c) ssum += __expf(lsh[wv][c] - mx);
      out[r * NCLS + d] = __expf(lg - mx) / ssum;
    }
  }
}

// -----------------------------------------------------------------------
extern "C" void kernel_launch(void* const* d_in, const int* in_sizes, int n_in,
                              void* d_out, int out_size, void* d_ws, size_t ws_size,
                              hipStream_t stream) {
  (void)in_sizes; (void)n_in; (void)out_size;
  const float* x  = (const float*)d_in[0];
  const float* wq = (const float*)d_in[1];
  const float* wk = (const float*)d_in[2];
  const float* wv = (const float*)d_in[3];
  const float* bn_a_gamma = (const float*)d_in[4];
  const float* bn_a_beta  = (const float*)d_in[5];
  const float* bn_a_mean  = (const float*)d_in[6];
  const float* bn_a_var   = (const float*)d_in[7];
  const float* w0 = (const float*)d_in[8];
  const float* b0 = (const float*)d_in[9];
  const float* w1 = (const float*)d_in[10];
  const float* b1 = (const float*)d_in[11];
  const float* bn1_gamma = (const float*)d_in[12];
  const float* bn1_beta  = (const float*)d_in[13];
  const float* bn1_mean  = (const float*)d_in[14];
  const float* bn1_var   = (const float*)d_in[15];
  const float* wd = (const float*)d_in[16];
  const float* bd = (const float*)d_in[17];
  float* out = (float*)d_out;

  char* cur = (char*)d_ws;
  float* pe = (float*)cur; cur += (size_t)TT * FF * 4;
  short* q  = (short*)cur; cur += (size_t)M * DD * 2;
  short* k  = (short*)cur; cur += (size_t)M * DD * 2;
  short* vt = (short*)cur; cur += (size_t)M * DD * 2;
  short* o2 = (short*)cur; cur += (size_t)M * DD * 2;
  float* x1 = (float*)cur; cur += (size_t)M * DD * 4;
  const size_t used = (size_t)(cur - (char*)d_ws);
  int S = 4;
  while (S > 1 && used + (size_t)S * ((size_t)M * DD + M) * 4 > ws_size) S >>= 1;
  float* po = (float*)cur;
  float* pl = po + (size_t)S * M * DD;

  pe_kernel<<<dim3(TT * FF / 256), dim3(256), 0, stream>>>(pe);
  proj_kernel<<<dim3(M / 128, 4), dim3(256), 0, stream>>>(
      x, pe, wq, wk, wv, w1, b1, q, k, vt, o2);
  attn_kernel<<<dim3(TT / 64, BB, S), dim3(256), 0, stream>>>(
      q, k, vt, po, pl, 16 / S);
  combine_kernel<<<dim3(M * DD / 256), dim3(256), 0, stream>>>(po, pl, x1, S);
  head_kernel<<<dim3(M / 32), dim3(256), 0, stream>>>(
      x1, o2, bn_a_gamma, bn_a_beta, bn_a_mean, bn_a_var,
      w0, b0, bn1_gamma, bn1_beta, bn1_mean, bn1_var, wd, bd, out);
}